// Round 1
// 412.209 us; speedup vs baseline: 1.1376x; 1.1376x over previous
//
#include <hip/hip_runtime.h>

#define TT 32768          // tokens
#define HH 2048           // hidden
#define NE 64             // experts
#define TOPK 8
#define BKC 64            // K-chunk
#define NCH (HH / BKC)    // 32 chunks

#define W_OFF 0
#define I_OFF (TT * TOPK)                 // 262144
#define P_OFF (2 * TT * TOPK)             // 524288
#define B_OFF (P_OFF + (size_t)TT * NE)   // 2621440

typedef __attribute__((ext_vector_type(8))) short short8;
typedef __attribute__((ext_vector_type(4))) float floatx4;

// swizzled ushort index of the 8-bf16 granule (row t, granule g in 0..7):
// granule slot = g ^ (t & 7) -> frag reads and staging writes conflict-free.
#define SWZ(t, g) (((t) << 6) + ((((g) ^ ((t)&7))) << 3))

// Exact truncation split: f = h0 + h1 + h2 + eps, |eps| <~ 2^-22 |f|.
__device__ __forceinline__ void split3(const float4 v, ushort4& o0, ushort4& o1, ushort4& o2)
{
    const float* vf = (const float*)&v;
    ushort* p0 = (ushort*)&o0; ushort* p1 = (ushort*)&o1; ushort* p2 = (ushort*)&o2;
#pragma unroll
    for (int i = 0; i < 4; ++i) {
        float f = vf[i];
        unsigned u0 = __float_as_uint(f);
        float h0 = __uint_as_float(u0 & 0xffff0000u);
        float r1 = f - h0;
        unsigned u1 = __float_as_uint(r1);
        float h1 = __uint_as_float(u1 & 0xffff0000u);
        float r2 = r1 - h1;
        unsigned u2 = __float_as_uint(r2);
        p0[i] = (ushort)(u0 >> 16);
        p1[i] = (ushort)(u1 >> 16);
        p2[i] = (ushort)(u2 >> 16);
    }
}

// ---------------------------------------------------------------------------
// GEMM-only kernel: 32 tokens x 64 experts per block, 1024 blocks.
// LDS 36 KB -> 4 blocks/CU (16 waves/CU) vs previous 2 -> 2x latency hiding.
// Same split3 / SWZ / MFMA accumulation order as the verified kernel, so
// logits are bitwise identical. Stores logits directly to out+P_OFF.
// Wave grid 2x2: wave (wm,wn) owns tokens [wm*16,+16), experts [wn*32,+32).
// ---------------------------------------------------------------------------
__global__ __launch_bounds__(256, 4) void gate_gemm(
    const float* __restrict__ x, const float* __restrict__ gw,
    float* __restrict__ logits)
{
    __shared__ ushort xp[3][32 * 64];   // x  planes, swizzled (4 KB each)
    __shared__ ushort gp[3][64 * 64];   // gw planes (8 KB each)

    const int tid = threadIdx.x;
    const int lane = tid & 63;
    const int wv = tid >> 6;
    const int wm = wv & 1, wn = wv >> 1;
    const int lr = lane & 15;
    const int lq = lane >> 4;
    const int tok0 = blockIdx.x * 32;

    floatx4 accB[2], accS[2];
#pragma unroll
    for (int j = 0; j < 2; ++j) { accB[j] = (floatx4)0.f; accS[j] = (floatx4)0.f; }

    const int sr = tid >> 4;            // staging sub-row 0..15
    const int sf = tid & 15;            // staging float4-group 0..15

    float4 px[2], pg[4];
#pragma unroll
    for (int it = 0; it < 2; ++it)
        px[it] = *(const float4*)&x[(size_t)(tok0 + it * 16 + sr) * HH + sf * 4];
#pragma unroll
    for (int it = 0; it < 4; ++it)
        pg[it] = *(const float4*)&gw[(size_t)(it * 16 + sr) * HH + sf * 4];

    for (int c = 0; c < NCH; ++c) {
        __syncthreads();                // previous chunk's frag reads done
#pragma unroll
        for (int it = 0; it < 2; ++it) {
            const int rr = it * 16 + sr;
            const int xi = SWZ(rr, sf >> 1) + ((sf & 1) << 2);
            ushort4 a0, a1, a2;
            split3(px[it], a0, a1, a2);
            *(ushort4*)&xp[0][xi] = a0;
            *(ushort4*)&xp[1][xi] = a1;
            *(ushort4*)&xp[2][xi] = a2;
        }
#pragma unroll
        for (int it = 0; it < 4; ++it) {
            const int rr = it * 16 + sr;
            const int gi = SWZ(rr, sf >> 1) + ((sf & 1) << 2);
            ushort4 a0, a1, a2;
            split3(pg[it], a0, a1, a2);
            *(ushort4*)&gp[0][gi] = a0;
            *(ushort4*)&gp[1][gi] = a1;
            *(ushort4*)&gp[2][gi] = a2;
        }
        __syncthreads();                // planes ready
        if (c + 1 < NCH) {
            const int k0 = (c + 1) * BKC;
#pragma unroll
            for (int it = 0; it < 2; ++it)
                px[it] = *(const float4*)&x[(size_t)(tok0 + it * 16 + sr) * HH + k0 + sf * 4];
#pragma unroll
            for (int it = 0; it < 4; ++it)
                pg[it] = *(const float4*)&gw[(size_t)(it * 16 + sr) * HH + k0 + sf * 4];
        }
#pragma unroll
        for (int s = 0; s < 2; ++s) {
            const int g = s * 4 + lq;
            short8 a[3], b[2][3];
            const int t = wm * 16 + lr;
            const int ai = SWZ(t, g);
#pragma unroll
            for (int p = 0; p < 3; ++p) a[p] = *(const short8*)&xp[p][ai];
#pragma unroll
            for (int nt = 0; nt < 2; ++nt) {
                const int e = wn * 32 + nt * 16 + lr;
                const int bi = SWZ(e, g);
#pragma unroll
                for (int p = 0; p < 3; ++p) b[nt][p] = *(const short8*)&gp[p][bi];
            }
#pragma unroll
            for (int nt = 0; nt < 2; ++nt) {
                accB[nt] = __builtin_amdgcn_mfma_f32_16x16x32_bf16(a[0], b[nt][0], accB[nt], 0, 0, 0);
                accS[nt] = __builtin_amdgcn_mfma_f32_16x16x32_bf16(a[0], b[nt][1], accS[nt], 0, 0, 0);
                accS[nt] = __builtin_amdgcn_mfma_f32_16x16x32_bf16(a[1], b[nt][0], accS[nt], 0, 0, 0);
                accS[nt] = __builtin_amdgcn_mfma_f32_16x16x32_bf16(a[0], b[nt][2], accS[nt], 0, 0, 0);
                accS[nt] = __builtin_amdgcn_mfma_f32_16x16x32_bf16(a[1], b[nt][1], accS[nt], 0, 0, 0);
                accS[nt] = __builtin_amdgcn_mfma_f32_16x16x32_bf16(a[2], b[nt][0], accS[nt], 0, 0, 0);
            }
        }
    }

    // C/D layout (verified m89/m91): col = lane&15 (expert), row = quad*4+reg
#pragma unroll
    for (int nt = 0; nt < 2; ++nt)
#pragma unroll
        for (int rg = 0; rg < 4; ++rg) {
            const int t = wm * 16 + lq * 4 + rg;
            const int e = wn * 32 + nt * 16 + lr;
            logits[(size_t)(tok0 + t) * NE + e] = accB[nt][rg] + accS[nt][rg];
        }
}

// ---------------------------------------------------------------------------
// Epilogue: one token per THREAD, 64-expert row fully in registers.
// No cross-lane shuffles at all; ~2k pipelined VALU ops per token.
// Reads logits in-place from out+P_OFF, overwrites with probs.
// Tree sum reproduces the previous butterfly's exact pairwise order;
// argmax strict-> with first-match keeps the lowest-index tiebreak.
// Outputs are bitwise identical to the previous (passing) kernel.
// ---------------------------------------------------------------------------
__global__ __launch_bounds__(64) void epilogue_k(
    const float* __restrict__ eb, const float* __restrict__ noise,
    float* __restrict__ out, int* __restrict__ counts)
{
    __shared__ float s_eb[NE];
    __shared__ int lc[NE];
    const int tid = threadIdx.x;                 // 0..63
    const int t = blockIdx.x * 64 + tid;         // token
    s_eb[tid] = eb[tid];
    lc[tid] = 0;
    __syncthreads();

    float* probs = out + P_OFF;
    const float4* lrow = (const float4*)&probs[(size_t)t * NE];
    const float4* nrow = (const float4*)&noise[(size_t)t * NE];

    float v[NE];
#pragma unroll
    for (int j = 0; j < 16; ++j) {
        float4 lg = lrow[j];
        float4 nz = nrow[j];
        v[4 * j + 0] = lg.x + nz.x * 0.01f + s_eb[4 * j + 0];
        v[4 * j + 1] = lg.y + nz.y * 0.01f + s_eb[4 * j + 1];
        v[4 * j + 2] = lg.z + nz.z * 0.01f + s_eb[4 * j + 2];
        v[4 * j + 3] = lg.w + nz.w * 0.01f + s_eb[4 * j + 3];
    }

    float m = v[0];
#pragma unroll
    for (int i = 1; i < NE; ++i) m = fmaxf(m, v[i]);

#pragma unroll
    for (int i = 0; i < NE; ++i) v[i] = expf(v[i] - m);

    // balanced pairwise tree == previous butterfly reduction, bitwise
    float tr[32];
#pragma unroll
    for (int i = 0; i < 32; ++i) tr[i] = v[2 * i] + v[2 * i + 1];
#pragma unroll
    for (int i = 0; i < 16; ++i) tr[i] = tr[2 * i] + tr[2 * i + 1];
#pragma unroll
    for (int i = 0; i < 8; ++i) tr[i] = tr[2 * i] + tr[2 * i + 1];
#pragma unroll
    for (int i = 0; i < 4; ++i) tr[i] = tr[2 * i] + tr[2 * i + 1];
#pragma unroll
    for (int i = 0; i < 2; ++i) tr[i] = tr[2 * i] + tr[2 * i + 1];
    const float inv = 1.f / (tr[0] + tr[1]);

#pragma unroll
    for (int i = 0; i < NE; ++i) v[i] = v[i] * inv;   // normalized probs

    float4* prow = (float4*)&probs[(size_t)t * NE];
#pragma unroll
    for (int j = 0; j < 16; ++j)
        prow[j] = make_float4(v[4 * j + 0], v[4 * j + 1], v[4 * j + 2], v[4 * j + 3]);

    // top-8 on normalized probs (same ordering domain as previous kernel)
    float wq[TOPK];
    int iq[TOPK];
    float wsum = 0.f;
#pragma unroll
    for (int r = 0; r < TOPK; ++r) {
        float bv = v[0]; int bi = 0;
#pragma unroll
        for (int i = 1; i < NE; ++i)
            if (v[i] > bv) { bv = v[i]; bi = i; }
        wsum += bv;
        wq[r] = bv;
        iq[r] = bi;
#pragma unroll
        for (int i = 0; i < NE; ++i)
            if (i == bi) v[i] = -1.f;
    }
    const float winv = 1.f / wsum;

    float4* wrow = (float4*)&out[W_OFF + (size_t)t * TOPK];
    wrow[0] = make_float4(wq[0] * winv, wq[1] * winv, wq[2] * winv, wq[3] * winv);
    wrow[1] = make_float4(wq[4] * winv, wq[5] * winv, wq[6] * winv, wq[7] * winv);
    float4* irow = (float4*)&out[I_OFF + (size_t)t * TOPK];
    irow[0] = make_float4((float)iq[0], (float)iq[1], (float)iq[2], (float)iq[3]);
    irow[1] = make_float4((float)iq[4], (float)iq[5], (float)iq[6], (float)iq[7]);

#pragma unroll
    for (int r = 0; r < TOPK; ++r) atomicAdd(&lc[iq[r]], 1);
    __syncthreads();
    if (lc[tid]) atomicAdd(&counts[tid], lc[tid]);
}

__global__ void zero_counts_k(int* c)
{
    if (threadIdx.x < NE) c[threadIdx.x] = 0;
}

// sign(load - 1/64) computed exactly: counts/2^18 is exact in fp32
__global__ void bias_k(const int* __restrict__ c, const float* __restrict__ eb,
                       float* __restrict__ out)
{
    int e = threadIdx.x;
    if (e < NE) {
        float load = (float)c[e] * (1.0f / 262144.0f);
        float err = load - 0.015625f;
        float sg = (err > 0.f) ? 1.f : ((err < 0.f) ? -1.f : 0.f);
        out[B_OFF + e] = eb[e] - 0.001f * sg;
    }
}

extern "C" void kernel_launch(void* const* d_in, const int* in_sizes, int n_in,
                              void* d_out, int out_size, void* d_ws, size_t ws_size,
                              hipStream_t stream)
{
    const float* x     = (const float*)d_in[0];
    const float* gw    = (const float*)d_in[1];
    const float* eb    = (const float*)d_in[2];
    const float* noise = (const float*)d_in[3];
    float* out = (float*)d_out;
    int* counts = (int*)d_ws;

    hipLaunchKernelGGL(zero_counts_k, dim3(1), dim3(64), 0, stream, counts);
    hipLaunchKernelGGL(gate_gemm, dim3(TT / 32), dim3(256), 0, stream,
                       x, gw, out + P_OFF);
    hipLaunchKernelGGL(epilogue_k, dim3(TT / 64), dim3(64), 0, stream,
                       eb, noise, out, counts);
    hipLaunchKernelGGL(bias_k, dim3(1), dim3(64), 0, stream, counts, eb, out);
}